// Round 8
// baseline (8676.685 us; speedup 1.0000x reference)
//
#include <hip/hip_runtime.h>

#define TT 256
#define BB 256
#define SW 3100.0f

typedef __attribute__((ext_vector_type(4))) int i32x4;

// sigma(x) = 1/(1+2^(-x*log2e)) : v_mul + v_exp + v_add + v_rcp
__device__ __forceinline__ float fsig(float x) {
  return __builtin_amdgcn_rcpf(1.0f + __builtin_amdgcn_exp2f(-1.44269504f * x));
}
// tanh(x) = 2*sigma(2x) - 1 : 5 VALU, no fabs/copysign/div
__device__ __forceinline__ float ftanh(float x) {
  float t = __builtin_amdgcn_rcpf(1.0f + __builtin_amdgcn_exp2f(-2.88539008f * x));
  return __builtin_fmaf(2.0f, t, -1.0f);
}
template <int ACT>
__device__ __forceinline__ float actf(float x) {
  if (ACT == 0) return fsig(x);
  if (ACT == 1) return fmaxf(x, 0.0f);
  if (ACT == 2) return ftanh(x);
  return x;  // identity
}

__device__ __forceinline__ i32x4 mi8(i32x4 a, i32x4 b, i32x4 c) {
  return __builtin_amdgcn_mfma_i32_16x16x64_i8(a, b, c, 0, 0, 0);
}

// [16][256] int8 plane, XOR-swizzled (verified rounds 1-6).
__device__ __forceinline__ int swz(int row, int k) { return row * 256 + (k ^ ((row & 7) << 4)); }

__device__ __forceinline__ i32x4 afrag(const char* P, int lane, int kbase) {
  int row = lane & 15;
  int k0 = kbase + ((lane >> 4) << 4);
  return *(const i32x4*)(P + swz(row, k0));
}

__device__ __forceinline__ int pack4(int a, int b, int c, int d) {
  return (a & 255) | ((b & 255) << 8) | ((c & 255) << 16) | ((d & 255) << 24);
}

// state s = hi/32 + lo/4096. hi clamped (med3, 1 inst); lo residual is
// mathematically <= 64 when hi unclamped -> no clamp needed.
__device__ __forceinline__ void put_sv(char* HI, char* LO, int row, int col, float s) {
  float hf = rintf(fminf(fmaxf(s * 32.0f, -127.0f), 127.0f));
  float lf = rintf((s - hf * (1.0f / 32.0f)) * 4096.0f);
  int a = swz(row, col);
  HI[a] = (char)(int)hf;
  LO[a] = (char)(int)lf;
}

// lgkmcnt-only barrier: orders LDS, does NOT drain the vmcnt prefetch queue.
__device__ __forceinline__ void barrier_ws() {
  asm volatile("s_waitcnt lgkmcnt(0)" ::: "memory");
  __builtin_amdgcn_s_barrier();
  __builtin_amdgcn_sched_barrier(0);
}

// Prefetch one 16-block (16 KB/wave) stage of weights into registers.
// The sched_barrier(0) pins the issue point: the compiler may NOT sink these
// loads toward their use (round-6 failure mode: VGPR=128, prefetch collapsed).
__device__ __forceinline__ void wload(i32x4 (&b)[16], const char* p) {
#pragma unroll
  for (int i = 0; i < 16; ++i) b[i] = *(const i32x4*)(p + i * 1024);
  __builtin_amdgcn_sched_barrier(0);
}

// Genotype GEMM MFMA core: A from LDS hi/lo planes, B from register buffer.
__device__ __forceinline__ void gmm(const char* SH, const char* SL, const i32x4 (&wb)[16],
                                    int lane, i32x4 (&ah)[4], i32x4 (&al)[4]) {
#pragma unroll
  for (int n = 0; n < 4; ++n) { ah[n] = (i32x4)(0); al[n] = (i32x4)(0); }
#pragma unroll
  for (int kt = 0; kt < 4; ++kt) {
    i32x4 Ah = afrag(SH, lane, kt * 64);
    i32x4 Al = afrag(SL, lane, kt * 64);
#pragma unroll
    for (int n = 0; n < 4; ++n) {
      ah[n] = mi8(Ah, wb[kt * 4 + n], ah[n]);
      al[n] = mi8(Al, wb[kt * 4 + n], al[n]);
    }
  }
}

template <int ACT, bool KEEP, bool STORE, bool MEAN>
__device__ __forceinline__ void gepi(const i32x4 (&ah)[4], const i32x4 (&al)[4],
                                     const float* spa, const float* spb, float* na, float* nb,
                                     float* ma, float* mb, char* SH, char* SL, int lrow,
                                     int ncol, int scol0) {
  const float INVG = 1.0f / (4096.0f * SW);
#pragma unroll
  for (int j = 0; j < 4; ++j) {
    float cA = ((float)ah[0][j] * 128.0f + (float)al[0][j]) * INVG;
    float hA = ((float)ah[2][j] * 128.0f + (float)al[2][j]) * INVG;
    float sA = __builtin_fmaf(fsig(cA), actf<ACT>(hA) - spa[j], spa[j]);
    float cB = ((float)ah[1][j] * 128.0f + (float)al[1][j]) * INVG;
    float hB = ((float)ah[3][j] * 128.0f + (float)al[3][j]) * INVG;
    float sB = __builtin_fmaf(fsig(cB), actf<ACT>(hB) - spb[j], spb[j]);
    if (MEAN) { ma[j] += sA; mb[j] += sB; }
    if (KEEP) { na[j] = sA; nb[j] = sB; }
    if (STORE) {
      put_sv(SH, SL, lrow + j, scol0 + ncol, sA);
      put_sv(SH, SL, lrow + j, scol0 + 16 + ncol, sB);
    }
  }
}

// Quantize + permute weights into per-wave lane-ordered int8 block streams.
// wq[wv][blk 0..159][lane][16]: blk 0-15 = W0 x-part (kt*4+nt), 16-31 = W0 h-part,
// 32+s*16+kt*4+nt = genotype stage s in consumption order Ws{0,1,2,3,4,6,5,7}.
__global__ void prep(const float* __restrict__ W0, const float* __restrict__ Ws,
                     char* __restrict__ wq) {
  int gid = blockIdx.x * 256 + threadIdx.x;
  const int mi[8] = {0, 1, 2, 3, 4, 6, 5, 7};
  int wv = gid / 163840;
  int r = gid - wv * 163840;
  int blk = r >> 10, b = r & 1023;
  int l = b >> 4, e = b & 15;
  int kloc = ((l >> 4) << 4) + e;
  int nt, n, k;
  float v;
  if (blk < 32) {
    int part = blk >> 4;  // 0=x rows, 1=h rows of W0
    int q = blk & 15;
    nt = q & 3;
    n = wv * 32 + (nt & 1) * 16 + ((nt >> 1) << 8) + (l & 15);
    k = part * 256 + (q >> 2) * 64 + kloc;
    v = W0[k * 512 + n];
  } else {
    int q = blk - 32;
    int s = q >> 4, w2 = q & 15;
    nt = w2 & 3;
    n = wv * 32 + (nt & 1) * 16 + ((nt >> 1) << 8) + (l & 15);
    k = (w2 >> 2) * 64 + kloc;
    v = Ws[(size_t)mi[s] * 131072 + k * 512 + n];
  }
  wq[gid] = (char)(int)rintf(v * SW);
}

__global__ __launch_bounds__(512, 2) void darts7(const float* __restrict__ X,
                                                 const float* __restrict__ Hin,
                                                 const char* __restrict__ WQ,
                                                 float* __restrict__ out) {
  __shared__ char A0XH[4096], A0XL[4096], A0HH[4096], A0HL[4096];
  __shared__ char SAH[4096], SAL[4096], SBH[4096], SBL[4096], SCH[4096], SCL[4096];

  const int tid = threadIdx.x, lane = tid & 63, wv = tid >> 6;  // 8 waves
  const int ncol = lane & 15, lrow = (lane >> 4) << 2;
  const int scol0 = wv * 32;
  const int rb = blockIdx.x * 16;
  const char* wsrc = WQ + (size_t)wv * 163840 + lane * 16;

  float hpa[4], hpb[4];
#pragma unroll
  for (int j = 0; j < 4; ++j) {
    hpa[j] = Hin[(rb + lrow + j) * 256 + scol0 + ncol];
    hpb[j] = Hin[(rb + lrow + j) * 256 + scol0 + 16 + ncol];
  }
#pragma unroll
  for (int j = 0; j < 4; ++j) {
    put_sv(A0HH, A0HL, lrow + j, scol0 + ncol, hpa[j]);
    put_sv(A0HH, A0HL, lrow + j, scol0 + 16 + ncol, hpb[j]);
  }

  // prologue: x(t=0) into regs; weight stage P0 into bufA
  float4 xr0, xr1;
  {
    int r = tid >> 5, c0 = (tid & 31) * 8;
    const float* xp = X + ((size_t)0 * BB + rb + r) * 256 + c0;
    xr0 = *(const float4*)xp;
    xr1 = *(const float4*)(xp + 4);
  }
  i32x4 bA[16], bB[16];
  wload(bA, wsrc);

  float s0a[4], s0b[4], s1a[4], s1b[4], s2a[4], s2b[4], s3a[4], s3b[4], s5a[4], s5b[4];
  float ma[4], mb[4], dmy[4];

  for (int t = 0; t < TT; ++t) {
    {  // stage x_t regs -> int8 hi/lo LDS planes (x = hi/16 + lo/2048)
      int r = tid >> 5, c0 = (tid & 31) * 8;
      float xs[8] = {xr0.x, xr0.y, xr0.z, xr0.w, xr1.x, xr1.y, xr1.z, xr1.w};
      int hb[8], lb[8];
#pragma unroll
      for (int j = 0; j < 8; ++j) {
        float hf = rintf(fminf(fmaxf(xs[j] * 16.0f, -127.0f), 127.0f));
        lb[j] = (int)rintf((xs[j] - hf * (1.0f / 16.0f)) * 2048.0f);
        hb[j] = (int)hf;
      }
      int a = swz(r, c0);
      *(int2*)(A0XH + a) = make_int2(pack4(hb[0], hb[1], hb[2], hb[3]),
                                     pack4(hb[4], hb[5], hb[6], hb[7]));
      *(int2*)(A0XL + a) = make_int2(pack4(lb[0], lb[1], lb[2], lb[3]),
                                     pack4(lb[4], lb[5], lb[6], lb[7]));
    }
    barrier_ws();

    // --- P0: W0 x-part (bA); prefetch P1 -> bB ---
    i32x4 axh[4], axl[4];
    wload(bB, wsrc + 16384);
#pragma unroll
    for (int n = 0; n < 4; ++n) { axh[n] = (i32x4)(0); axl[n] = (i32x4)(0); }
#pragma unroll
    for (int kt = 0; kt < 4; ++kt) {
      i32x4 Axh = afrag(A0XH, lane, kt * 64);
      i32x4 Axl = afrag(A0XL, lane, kt * 64);
#pragma unroll
      for (int n = 0; n < 4; ++n) {
        axh[n] = mi8(Axh, bA[kt * 4 + n], axh[n]);
        axl[n] = mi8(Axl, bA[kt * 4 + n], axl[n]);
      }
    }
    // x-hi unit (1/16) = 2x state-hi unit (1/32); x-lo (1/2048) = 2x state-lo: double accs
#pragma unroll
    for (int n = 0; n < 4; ++n) { axh[n] = axh[n] + axh[n]; axl[n] = axl[n] + axl[n]; }

    // --- P1: W0 h-part (bB) accumulates into scaled accs; prefetch P2 -> bA ---
    wload(bA, wsrc + 2 * 16384);
#pragma unroll
    for (int kt = 0; kt < 4; ++kt) {
      i32x4 Ahh = afrag(A0HH, lane, kt * 64);
      i32x4 Ahl = afrag(A0HL, lane, kt * 64);
#pragma unroll
      for (int n = 0; n < 4; ++n) {
        axh[n] = mi8(Ahh, bB[kt * 4 + n], axh[n]);
        axl[n] = mi8(Ahl, bB[kt * 4 + n], axl[n]);
      }
    }
    gepi<2, true, true, false>(axh, axl, hpa, hpb, s0a, s0b, ma, mb, SAH, SAL, lrow, ncol, scol0);
    barrier_ws();

#pragma unroll
    for (int j = 0; j < 4; ++j) { ma[j] = 0.f; mb[j] = 0.f; }

    i32x4 gh[4], gl[4];
    // --- P2: s1 = sigmoid step (Ws0) from SA(s0) -> SB; prefetch P3 -> bB ---
    wload(bB, wsrc + 3 * 16384);
    gmm(SAH, SAL, bA, lane, gh, gl);
    gepi<0, true, true, true>(gh, gl, s0a, s0b, s1a, s1b, ma, mb, SBH, SBL, lrow, ncol, scol0);
    barrier_ws();

    // --- P3: s2 relu -> SA (bB); prefetch P4 -> bA ---
    wload(bA, wsrc + 4 * 16384);
    gmm(SBH, SBL, bB, lane, gh, gl);
    gepi<1, true, true, true>(gh, gl, s1a, s1b, s2a, s2b, ma, mb, SAH, SAL, lrow, ncol, scol0);
    // --- P4: s3 relu -> SC (bA); prefetch P5 -> bB ---
    wload(bB, wsrc + 5 * 16384);
    gmm(SBH, SBL, bA, lane, gh, gl);
    gepi<1, true, true, true>(gh, gl, s1a, s1b, s3a, s3b, ma, mb, SCH, SCL, lrow, ncol, scol0);
    // --- P5: s4 identity, no store (bB); prefetch P6 -> bA ---
    wload(bA, wsrc + 6 * 16384);
    gmm(SBH, SBL, bB, lane, gh, gl);
    gepi<3, false, false, true>(gh, gl, s1a, s1b, dmy, dmy, ma, mb, nullptr, nullptr, lrow, ncol, scol0);
    barrier_ws();

    // --- P6: s5 tanh (Ws4) from SA(s2) -> SB (bA); prefetch P7 -> bB ---
    wload(bB, wsrc + 7 * 16384);
    gmm(SAH, SAL, bA, lane, gh, gl);
    gepi<2, true, true, true>(gh, gl, s2a, s2b, s5a, s5b, ma, mb, SBH, SBL, lrow, ncol, scol0);
    // --- P7: s7 tanh (Ws6) from SC(s3), no store (bB); prefetch P8 -> bA ---
    wload(bA, wsrc + 8 * 16384);
    gmm(SCH, SCL, bB, lane, gh, gl);
    gepi<2, false, false, true>(gh, gl, s3a, s3b, dmy, dmy, ma, mb, nullptr, nullptr, lrow, ncol, scol0);
    // prefetch x(t+1) into regs (HBM latency hides under stage E)
    if (t + 1 < TT) {
      int r = tid >> 5, c0 = (tid & 31) * 8;
      const float* xp = X + ((size_t)(t + 1) * BB + rb + r) * 256 + c0;
      xr0 = *(const float4*)xp;
      xr1 = *(const float4*)(xp + 4);
    }
    barrier_ws();

    // --- P8: s6 sig (Ws5) from SB(s5) (bA); prefetch P9 -> bB ---
    wload(bB, wsrc + 9 * 16384);
    gmm(SBH, SBL, bA, lane, gh, gl);
    gepi<0, false, false, true>(gh, gl, s5a, s5b, dmy, dmy, ma, mb, nullptr, nullptr, lrow, ncol, scol0);
    // --- P9: s8 relu (Ws7) from SB(s5) (bB); prefetch P0 of t+1 -> bA ---
    wload(bA, wsrc);
    gmm(SBH, SBL, bB, lane, gh, gl);
    gepi<1, false, false, true>(gh, gl, s5a, s5b, dmy, dmy, ma, mb, nullptr, nullptr, lrow, ncol, scol0);

    // h = mean(states 1..8); store hiddens[t]; restage h
#pragma unroll
    for (int j = 0; j < 4; ++j) { hpa[j] = ma[j] * 0.125f; hpb[j] = mb[j] * 0.125f; }
#pragma unroll
    for (int j = 0; j < 4; ++j) {
      size_t base = ((size_t)t * BB + rb + lrow + j) * 256;
      out[base + scol0 + ncol] = hpa[j];
      out[base + scol0 + 16 + ncol] = hpb[j];
    }
    if (t == TT - 1) {
#pragma unroll
      for (int j = 0; j < 4; ++j) {
        size_t base = ((size_t)TT * BB + rb + lrow + j) * 256;
        out[base + scol0 + ncol] = hpa[j];
        out[base + scol0 + 16 + ncol] = hpb[j];
      }
    }
#pragma unroll
    for (int j = 0; j < 4; ++j) {
      put_sv(A0HH, A0HL, lrow + j, scol0 + ncol, hpa[j]);
      put_sv(A0HH, A0HL, lrow + j, scol0 + 16 + ncol, hpb[j]);
    }
    // loop-top barrier orders A0X/A0H LDS writes for the next W0 stage
  }
}

extern "C" void kernel_launch(void* const* d_in, const int* in_sizes, int n_in,
                              void* d_out, int out_size, void* d_ws, size_t ws_size,
                              hipStream_t stream) {
  (void)in_sizes; (void)n_in; (void)out_size; (void)ws_size;
  const float* X = (const float*)d_in[0];
  const float* Hin = (const float*)d_in[1];
  const float* W0 = (const float*)d_in[2];
  const float* Ws = (const float*)d_in[3];
  char* wq = (char*)d_ws;  // 8 waves * 160 KiB = 1.28 MB
  float* out = (float*)d_out;

  prep<<<5120, 256, 0, stream>>>(W0, Ws, wq);
  darts7<<<16, 512, 0, stream>>>(X, Hin, wq, out);
}

// Round 9
// 3543.794 us; speedup vs baseline: 2.4484x; 2.4484x over previous
//
#include <hip/hip_runtime.h>

#define TT 256
#define BB 256
#define SW 3100.0f

typedef __attribute__((ext_vector_type(4))) int i32x4;

// --- inline-asm load machinery: loads that NO compiler pass can sink ---
#define GLOAD_(dst, vo, sb, IMM) \
  asm volatile("global_load_dwordx4 %0, %1, %2 offset:" #IMM \
               : "=v"(dst) : "v"(vo), "s"(sb))
#define GLOAD(dst, vo, sb, IMM) GLOAD_(dst, vo, sb, IMM)

#define VMWAIT_(N) \
  do { asm volatile("s_waitcnt vmcnt(" #N ")" ::: "memory"); \
       __builtin_amdgcn_sched_barrier(0); } while (0)
#define VMWAIT(N) VMWAIT_(N)

__device__ __forceinline__ const char* uniform_ptr(const void* p) {
  uint64_t u = (uint64_t)(uintptr_t)p;
  uint32_t lo = __builtin_amdgcn_readfirstlane((uint32_t)u);
  uint32_t hi = __builtin_amdgcn_readfirstlane((uint32_t)(u >> 32));
  return (const char*)(uintptr_t)(((uint64_t)hi << 32) | lo);
}

// Issue one 16-KB weight stage (16 x dwordx4 per lane) into a register buffer.
__device__ __forceinline__ void wissue(i32x4 (&b)[16], const char* sb, int vo) {
  GLOAD(b[0], vo, sb, 0);  GLOAD(b[1], vo, sb, 1024);
  GLOAD(b[2], vo, sb, 2048); GLOAD(b[3], vo, sb, 3072);
  const char* s1 = sb + 4096;
  GLOAD(b[4], vo, s1, 0);  GLOAD(b[5], vo, s1, 1024);
  GLOAD(b[6], vo, s1, 2048); GLOAD(b[7], vo, s1, 3072);
  const char* s2 = sb + 8192;
  GLOAD(b[8], vo, s2, 0);  GLOAD(b[9], vo, s2, 1024);
  GLOAD(b[10], vo, s2, 2048); GLOAD(b[11], vo, s2, 3072);
  const char* s3 = sb + 12288;
  GLOAD(b[12], vo, s3, 0); GLOAD(b[13], vo, s3, 1024);
  GLOAD(b[14], vo, s3, 2048); GLOAD(b[15], vo, s3, 3072);
}

__device__ __forceinline__ void xissue(float4& a, float4& b, const char* sb, int vo) {
  GLOAD(a, vo, sb, 0);
  GLOAD(b, vo, sb, 16);
}

// sigma(x) = 1/(1+2^(-x*log2e)); tanh(x) = 2*sigma(2x)-1
__device__ __forceinline__ float fsig(float x) {
  return __builtin_amdgcn_rcpf(1.0f + __builtin_amdgcn_exp2f(-1.44269504f * x));
}
__device__ __forceinline__ float ftanh(float x) {
  float t = __builtin_amdgcn_rcpf(1.0f + __builtin_amdgcn_exp2f(-2.88539008f * x));
  return __builtin_fmaf(2.0f, t, -1.0f);
}
template <int ACT>
__device__ __forceinline__ float actf(float x) {
  if (ACT == 0) return fsig(x);
  if (ACT == 1) return fmaxf(x, 0.0f);
  if (ACT == 2) return ftanh(x);
  return x;  // identity
}

__device__ __forceinline__ i32x4 mi8(i32x4 a, i32x4 b, i32x4 c) {
  return __builtin_amdgcn_mfma_i32_16x16x64_i8(a, b, c, 0, 0, 0);
}

// [16][256] int8 plane, XOR-swizzled (verified rounds 1-8).
__device__ __forceinline__ int swz(int row, int k) { return row * 256 + (k ^ ((row & 7) << 4)); }

__device__ __forceinline__ i32x4 afrag(const char* P, int lane, int kbase) {
  int row = lane & 15;
  int k0 = kbase + ((lane >> 4) << 4);
  return *(const i32x4*)(P + swz(row, k0));
}

__device__ __forceinline__ int pack4(int a, int b, int c, int d) {
  return (a & 255) | ((b & 255) << 8) | ((c & 255) << 16) | ((d & 255) << 24);
}

// state s = hi/32 + lo/4096
__device__ __forceinline__ void put_sv(char* HI, char* LO, int row, int col, float s) {
  float hf = rintf(fminf(fmaxf(s * 32.0f, -127.0f), 127.0f));
  float lf = rintf((s - hf * (1.0f / 32.0f)) * 4096.0f);
  int a = swz(row, col);
  HI[a] = (char)(int)hf;
  LO[a] = (char)(int)lf;
}

// lgkmcnt-only barrier: orders LDS, does NOT drain the vmcnt prefetch queue.
__device__ __forceinline__ void barrier_ws() {
  asm volatile("s_waitcnt lgkmcnt(0)" ::: "memory");
  __builtin_amdgcn_s_barrier();
  __builtin_amdgcn_sched_barrier(0);
}

__device__ __forceinline__ void gmm(const char* SH, const char* SL, const i32x4 (&wb)[16],
                                    int lane, i32x4 (&ah)[4], i32x4 (&al)[4]) {
#pragma unroll
  for (int n = 0; n < 4; ++n) { ah[n] = (i32x4)(0); al[n] = (i32x4)(0); }
#pragma unroll
  for (int kt = 0; kt < 4; ++kt) {
    i32x4 Ah = afrag(SH, lane, kt * 64);
    i32x4 Al = afrag(SL, lane, kt * 64);
#pragma unroll
    for (int n = 0; n < 4; ++n) {
      ah[n] = mi8(Ah, wb[kt * 4 + n], ah[n]);
      al[n] = mi8(Al, wb[kt * 4 + n], al[n]);
    }
  }
}

template <int ACT, bool KEEP, bool STORE, bool MEAN>
__device__ __forceinline__ void gepi(const i32x4 (&ah)[4], const i32x4 (&al)[4],
                                     const float* spa, const float* spb, float* na, float* nb,
                                     float* ma, float* mb, char* SH, char* SL, int lrow,
                                     int ncol, int scol0) {
  const float INVG = 1.0f / (4096.0f * SW);
#pragma unroll
  for (int j = 0; j < 4; ++j) {
    float cA = ((float)ah[0][j] * 128.0f + (float)al[0][j]) * INVG;
    float hA = ((float)ah[2][j] * 128.0f + (float)al[2][j]) * INVG;
    float sA = __builtin_fmaf(fsig(cA), actf<ACT>(hA) - spa[j], spa[j]);
    float cB = ((float)ah[1][j] * 128.0f + (float)al[1][j]) * INVG;
    float hB = ((float)ah[3][j] * 128.0f + (float)al[3][j]) * INVG;
    float sB = __builtin_fmaf(fsig(cB), actf<ACT>(hB) - spb[j], spb[j]);
    if (MEAN) { ma[j] += sA; mb[j] += sB; }
    if (KEEP) { na[j] = sA; nb[j] = sB; }
    if (STORE) {
      put_sv(SH, SL, lrow + j, scol0 + ncol, sA);
      put_sv(SH, SL, lrow + j, scol0 + 16 + ncol, sB);
    }
  }
}

// Quantize + permute weights into per-wave lane-ordered int8 block streams.
__global__ void prep(const float* __restrict__ W0, const float* __restrict__ Ws,
                     char* __restrict__ wq) {
  int gid = blockIdx.x * 256 + threadIdx.x;
  const int mi[8] = {0, 1, 2, 3, 4, 6, 5, 7};
  int wv = gid / 163840;
  int r = gid - wv * 163840;
  int blk = r >> 10, b = r & 1023;
  int l = b >> 4, e = b & 15;
  int kloc = ((l >> 4) << 4) + e;
  int nt, n, k;
  float v;
  if (blk < 32) {
    int part = blk >> 4;  // 0=x rows, 1=h rows of W0
    int q = blk & 15;
    nt = q & 3;
    n = wv * 32 + (nt & 1) * 16 + ((nt >> 1) << 8) + (l & 15);
    k = part * 256 + (q >> 2) * 64 + kloc;
    v = W0[k * 512 + n];
  } else {
    int q = blk - 32;
    int s = q >> 4, w2 = q & 15;
    nt = w2 & 3;
    n = wv * 32 + (nt & 1) * 16 + ((nt >> 1) << 8) + (l & 15);
    k = (w2 >> 2) * 64 + kloc;
    v = Ws[(size_t)mi[s] * 131072 + k * 512 + n];
  }
  wq[gid] = (char)(int)rintf(v * SW);
}

__global__ __launch_bounds__(512, 2) void darts8(const float* __restrict__ X,
                                                 const float* __restrict__ Hin,
                                                 const char* __restrict__ WQ,
                                                 float* __restrict__ out) {
  __shared__ char A0XH[4096], A0XL[4096], A0HH[4096], A0HL[4096];
  __shared__ char SAH[4096], SAL[4096], SBH[4096], SBL[4096], SCH[4096], SCL[4096];

  const int tid = threadIdx.x, lane = tid & 63, wv = tid >> 6;  // 8 waves
  const int ncol = lane & 15, lrow = (lane >> 4) << 2;
  const int scol0 = wv * 32;
  const int rb = blockIdx.x * 16;
  const char* wsrc = uniform_ptr(WQ + (size_t)wv * 163840);  // SGPR-resident base
  const int wvoff = lane * 16;                                // weight voffset
  const int xvoff = ((tid >> 5) << 10) + ((tid & 31) << 5);   // x voffset (bytes)

  float hpa[4], hpb[4];
#pragma unroll
  for (int j = 0; j < 4; ++j) {
    hpa[j] = Hin[(rb + lrow + j) * 256 + scol0 + ncol];
    hpb[j] = Hin[(rb + lrow + j) * 256 + scol0 + 16 + ncol];
  }
#pragma unroll
  for (int j = 0; j < 4; ++j) {
    put_sv(A0HH, A0HL, lrow + j, scol0 + ncol, hpa[j]);
    put_sv(A0HH, A0HL, lrow + j, scol0 + 16 + ncol, hpb[j]);
  }

  // prologue: issue x(t=0) [2 ops], then P0 weights [16 ops] -> outstanding 18
  float4 xr0, xr1;
  i32x4 bA[16], bB[16];
  xissue(xr0, xr1, uniform_ptr(X + (size_t)rb * 256), xvoff);
  wissue(bA, wsrc, wvoff);

  float s0a[4], s0b[4], s1a[4], s1b[4], s2a[4], s2b[4], s3a[4], s3b[4], s5a[4], s5b[4];
  float ma[4], mb[4], dmy[4];

  for (int t = 0; t < TT; ++t) {
    VMWAIT(16);  // x ready (retires x + prior-iter stores; P0w stays in flight)
    {  // stage x_t regs -> int8 hi/lo LDS planes (x = hi/16 + lo/2048)
      int r = tid >> 5, c0 = (tid & 31) * 8;
      float xs[8] = {xr0.x, xr0.y, xr0.z, xr0.w, xr1.x, xr1.y, xr1.z, xr1.w};
      int hb[8], lb[8];
#pragma unroll
      for (int j = 0; j < 8; ++j) {
        float hf = rintf(fminf(fmaxf(xs[j] * 16.0f, -127.0f), 127.0f));
        lb[j] = (int)rintf((xs[j] - hf * (1.0f / 16.0f)) * 2048.0f);
        hb[j] = (int)hf;
      }
      int a = swz(r, c0);
      *(int2*)(A0XH + a) = make_int2(pack4(hb[0], hb[1], hb[2], hb[3]),
                                     pack4(hb[4], hb[5], hb[6], hb[7]));
      *(int2*)(A0XL + a) = make_int2(pack4(lb[0], lb[1], lb[2], lb[3]),
                                     pack4(lb[4], lb[5], lb[6], lb[7]));
    }
    barrier_ws();

    // --- P0: W0 x-part (bA); issue P1 -> bB ---
    i32x4 axh[4], axl[4];
    wissue(bB, wsrc + 16384, wvoff);
    VMWAIT(16);
#pragma unroll
    for (int n = 0; n < 4; ++n) { axh[n] = (i32x4)(0); axl[n] = (i32x4)(0); }
#pragma unroll
    for (int kt = 0; kt < 4; ++kt) {
      i32x4 Axh = afrag(A0XH, lane, kt * 64);
      i32x4 Axl = afrag(A0XL, lane, kt * 64);
#pragma unroll
      for (int n = 0; n < 4; ++n) {
        axh[n] = mi8(Axh, bA[kt * 4 + n], axh[n]);
        axl[n] = mi8(Axl, bA[kt * 4 + n], axl[n]);
      }
    }
    // x units are 2x state units: double the x accumulators before adding h terms
#pragma unroll
    for (int n = 0; n < 4; ++n) { axh[n] = axh[n] + axh[n]; axl[n] = axl[n] + axl[n]; }

    // --- P1: W0 h-part (bB); issue P2 -> bA ---
    wissue(bA, wsrc + 2 * 16384, wvoff);
    VMWAIT(16);
#pragma unroll
    for (int kt = 0; kt < 4; ++kt) {
      i32x4 Ahh = afrag(A0HH, lane, kt * 64);
      i32x4 Ahl = afrag(A0HL, lane, kt * 64);
#pragma unroll
      for (int n = 0; n < 4; ++n) {
        axh[n] = mi8(Ahh, bB[kt * 4 + n], axh[n]);
        axl[n] = mi8(Ahl, bB[kt * 4 + n], axl[n]);
      }
    }
    gepi<2, true, true, false>(axh, axl, hpa, hpb, s0a, s0b, ma, mb, SAH, SAL, lrow, ncol, scol0);
    barrier_ws();

#pragma unroll
    for (int j = 0; j < 4; ++j) { ma[j] = 0.f; mb[j] = 0.f; }

    i32x4 gh[4], gl[4];
    // --- P2: s1 (sigmoid, Ws0) from SA(s0) -> SB; issue P3 -> bB ---
    wissue(bB, wsrc + 3 * 16384, wvoff);
    VMWAIT(16);
    gmm(SAH, SAL, bA, lane, gh, gl);
    gepi<0, true, true, true>(gh, gl, s0a, s0b, s1a, s1b, ma, mb, SBH, SBL, lrow, ncol, scol0);
    barrier_ws();

    // --- P3: s2 relu -> SA; issue P4 -> bA ---
    wissue(bA, wsrc + 4 * 16384, wvoff);
    VMWAIT(16);
    gmm(SBH, SBL, bB, lane, gh, gl);
    gepi<1, true, true, true>(gh, gl, s1a, s1b, s2a, s2b, ma, mb, SAH, SAL, lrow, ncol, scol0);
    // --- P4: s3 relu -> SC; issue P5 -> bB ---
    wissue(bB, wsrc + 5 * 16384, wvoff);
    VMWAIT(16);
    gmm(SBH, SBL, bA, lane, gh, gl);
    gepi<1, true, true, true>(gh, gl, s1a, s1b, s3a, s3b, ma, mb, SCH, SCL, lrow, ncol, scol0);
    // --- P5: s4 identity (no store); issue P6 -> bA ---
    wissue(bA, wsrc + 6 * 16384, wvoff);
    VMWAIT(16);
    gmm(SBH, SBL, bB, lane, gh, gl);
    gepi<3, false, false, true>(gh, gl, s1a, s1b, dmy, dmy, ma, mb, nullptr, nullptr, lrow, ncol, scol0);
    barrier_ws();

    // --- P6: s5 tanh (Ws4) from SA(s2) -> SB; issue P7 -> bB ---
    wissue(bB, wsrc + 7 * 16384, wvoff);
    VMWAIT(16);
    gmm(SAH, SAL, bA, lane, gh, gl);
    gepi<2, true, true, true>(gh, gl, s2a, s2b, s5a, s5b, ma, mb, SBH, SBL, lrow, ncol, scol0);
    // --- P7: s7 tanh (Ws6) from SC(s3), no store; issue P8 -> bA ---
    wissue(bA, wsrc + 8 * 16384, wvoff);
    VMWAIT(16);
    gmm(SCH, SCL, bB, lane, gh, gl);
    gepi<2, false, false, true>(gh, gl, s3a, s3b, dmy, dmy, ma, mb, nullptr, nullptr, lrow, ncol, scol0);
    barrier_ws();

    // --- P8: s6 sig (Ws5) from SB(s5); issue P9 -> bB, then x(t+1) ---
    wissue(bB, wsrc + 9 * 16384, wvoff);
    {
      int tn = (t + 1 < TT) ? t + 1 : TT - 1;
      xissue(xr0, xr1, uniform_ptr(X + ((size_t)tn * BB + rb) * 256), xvoff);
    }
    VMWAIT(18);  // retires P8w exactly (P9w16 + x2 stay in flight)
    gmm(SBH, SBL, bA, lane, gh, gl);
    gepi<0, false, false, true>(gh, gl, s5a, s5b, dmy, dmy, ma, mb, nullptr, nullptr, lrow, ncol, scol0);
    // --- P9: s8 relu (Ws7) from SB(s5); issue P0 of t+1 -> bA ---
    wissue(bA, wsrc, wvoff);
    VMWAIT(18);  // retires P9w exactly (x2 + P0'w16 stay)
    gmm(SBH, SBL, bB, lane, gh, gl);
    gepi<1, false, false, true>(gh, gl, s5a, s5b, dmy, dmy, ma, mb, nullptr, nullptr, lrow, ncol, scol0);

    // h = mean(states 1..8); store hiddens[t]; restage h
#pragma unroll
    for (int j = 0; j < 4; ++j) { hpa[j] = ma[j] * 0.125f; hpb[j] = mb[j] * 0.125f; }
#pragma unroll
    for (int j = 0; j < 4; ++j) {
      size_t base = ((size_t)t * BB + rb + lrow + j) * 256;
      out[base + scol0 + ncol] = hpa[j];
      out[base + scol0 + 16 + ncol] = hpb[j];
    }
    if (t == TT - 1) {
#pragma unroll
      for (int j = 0; j < 4; ++j) {
        size_t base = ((size_t)TT * BB + rb + lrow + j) * 256;
        out[base + scol0 + ncol] = hpa[j];
        out[base + scol0 + 16 + ncol] = hpb[j];
      }
    }
#pragma unroll
    for (int j = 0; j < 4; ++j) {
      put_sv(A0HH, A0HL, lrow + j, scol0 + ncol, hpa[j]);
      put_sv(A0HH, A0HL, lrow + j, scol0 + 16 + ncol, hpb[j]);
    }
    // loop-top barrier orders A0X/A0H LDS writes for the next W0 stage
  }
  asm volatile("s_waitcnt vmcnt(0)" ::: "memory");  // drain tail loads/stores
}

extern "C" void kernel_launch(void* const* d_in, const int* in_sizes, int n_in,
                              void* d_out, int out_size, void* d_ws, size_t ws_size,
                              hipStream_t stream) {
  (void)in_sizes; (void)n_in; (void)out_size; (void)ws_size;
  const float* X = (const float*)d_in[0];
  const float* Hin = (const float*)d_in[1];
  const float* W0 = (const float*)d_in[2];
  const float* Ws = (const float*)d_in[3];
  char* wq = (char*)d_ws;  // 8 waves * 160 KiB = 1.28 MB
  float* out = (float*)d_out;

  prep<<<5120, 256, 0, stream>>>(W0, Ws, wq);
  darts8<<<16, 512, 0, stream>>>(X, Hin, wq, out);
}

// Round 10
// 2950.534 us; speedup vs baseline: 2.9407x; 1.2011x over previous
//
#include <hip/hip_runtime.h>

#define TT 256
#define BB 256
#define SW 3100.0f
#define WSTRIDE 81920  // 80 blocks * 1024 B per wave (10 stages x 8 blocks)

typedef __attribute__((ext_vector_type(4))) int i32x4;

// --- inline-asm load machinery: loads no compiler pass can sink (r9-verified) ---
#define GLOAD_(dst, vo, sb, IMM) \
  asm volatile("global_load_dwordx4 %0, %1, %2 offset:" #IMM \
               : "=v"(dst) : "v"(vo), "s"(sb))
#define GLOAD(dst, vo, sb, IMM) GLOAD_(dst, vo, sb, IMM)

#define VMWAIT_(N) \
  do { asm volatile("s_waitcnt vmcnt(" #N ")" ::: "memory"); \
       __builtin_amdgcn_sched_barrier(0); } while (0)
#define VMWAIT(N) VMWAIT_(N)

__device__ __forceinline__ const char* uniform_ptr(const void* p) {
  uint64_t u = (uint64_t)(uintptr_t)p;
  uint32_t lo = __builtin_amdgcn_readfirstlane((uint32_t)u);
  uint32_t hi = __builtin_amdgcn_readfirstlane((uint32_t)(u >> 32));
  return (const char*)(uintptr_t)(((uint64_t)hi << 32) | lo);
}

// Issue one 8-KB weight stage (8 x dwordx4 per lane) into a register buffer.
__device__ __forceinline__ void wissue(i32x4 (&b)[8], const char* sb, int vo) {
  GLOAD(b[0], vo, sb, 0);    GLOAD(b[1], vo, sb, 1024);
  GLOAD(b[2], vo, sb, 2048); GLOAD(b[3], vo, sb, 3072);
  const char* s1 = sb + 4096;
  GLOAD(b[4], vo, s1, 0);    GLOAD(b[5], vo, s1, 1024);
  GLOAD(b[6], vo, s1, 2048); GLOAD(b[7], vo, s1, 3072);
}

// sigma(x) = 1/(1+2^(-x*log2e)); tanh(x) = 2*sigma(2x)-1
__device__ __forceinline__ float fsig(float x) {
  return __builtin_amdgcn_rcpf(1.0f + __builtin_amdgcn_exp2f(-1.44269504f * x));
}
__device__ __forceinline__ float ftanh(float x) {
  float t = __builtin_amdgcn_rcpf(1.0f + __builtin_amdgcn_exp2f(-2.88539008f * x));
  return __builtin_fmaf(2.0f, t, -1.0f);
}
template <int ACT>
__device__ __forceinline__ float actf(float x) {
  if (ACT == 0) return fsig(x);
  if (ACT == 1) return fmaxf(x, 0.0f);
  if (ACT == 2) return ftanh(x);
  return x;  // identity
}

__device__ __forceinline__ i32x4 mi8(i32x4 a, i32x4 b, i32x4 c) {
  return __builtin_amdgcn_mfma_i32_16x16x64_i8(a, b, c, 0, 0, 0);
}

// [16][256] int8 plane, XOR-swizzled (verified rounds 1-9).
__device__ __forceinline__ int swz(int row, int k) { return row * 256 + (k ^ ((row & 7) << 4)); }

__device__ __forceinline__ i32x4 afrag(const char* P, int lane, int kbase) {
  int row = lane & 15;
  int k0 = kbase + ((lane >> 4) << 4);
  return *(const i32x4*)(P + swz(row, k0));
}

__device__ __forceinline__ int pack4(int a, int b, int c, int d) {
  return (a & 255) | ((b & 255) << 8) | ((c & 255) << 16) | ((d & 255) << 24);
}

// state s = hi/32 + lo/4096
__device__ __forceinline__ void put_sv(char* HI, char* LO, int row, int col, float s) {
  float hf = rintf(fminf(fmaxf(s * 32.0f, -127.0f), 127.0f));
  float lf = rintf((s - hf * (1.0f / 32.0f)) * 4096.0f);
  int a = swz(row, col);
  HI[a] = (char)(int)hf;
  LO[a] = (char)(int)lf;
}

// lgkmcnt-only barrier: orders LDS, does NOT drain the vmcnt prefetch queue.
__device__ __forceinline__ void barrier_ws() {
  asm volatile("s_waitcnt lgkmcnt(0)" ::: "memory");
  __builtin_amdgcn_s_barrier();
  __builtin_amdgcn_sched_barrier(0);
}

// Genotype GEMM core: 16 cols/wave -> accs {c_hi, c_lo, h_hi, h_lo}.
__device__ __forceinline__ void gmm8(const char* SH, const char* SL, const i32x4 (&wb)[8],
                                     int lane, i32x4& ch, i32x4& cl, i32x4& hh, i32x4& hl) {
  ch = (i32x4)(0); cl = (i32x4)(0); hh = (i32x4)(0); hl = (i32x4)(0);
#pragma unroll
  for (int kt = 0; kt < 4; ++kt) {
    i32x4 Ah = afrag(SH, lane, kt * 64);
    i32x4 Al = afrag(SL, lane, kt * 64);
    ch = mi8(Ah, wb[kt * 2 + 0], ch);
    hh = mi8(Ah, wb[kt * 2 + 1], hh);
    cl = mi8(Al, wb[kt * 2 + 0], cl);
    hl = mi8(Al, wb[kt * 2 + 1], hl);
  }
}

template <int ACT, bool KEEP, bool STORE>
__device__ __forceinline__ void gepi(const i32x4& ch, const i32x4& cl, const i32x4& hh,
                                     const i32x4& hl, const float* sp, float* sn, float* ma,
                                     char* SH, char* SL, int lrow, int sc) {
  const float INVG = 1.0f / (4096.0f * SW);
#pragma unroll
  for (int j = 0; j < 4; ++j) {
    float c = (float)(ch[j] * 128 + cl[j]) * INVG;
    float h = (float)(hh[j] * 128 + hl[j]) * INVG;
    float s = __builtin_fmaf(fsig(c), actf<ACT>(h) - sp[j], sp[j]);
    ma[j] += s;
    if (KEEP) sn[j] = s;
    if (STORE) put_sv(SH, SL, lrow + j, sc, s);
  }
}

// Quantize + permute weights into per-wave (16 waves) lane-ordered block streams.
// wq[wv][stage 0..9][sb 0..7][lane][16]: sb = kt*2 + pt; pt 0 = c-cols, 1 = h-cols.
// n = pt*256 + wv*16 + (l&15); k = kt*64 + (l>>4)*16 + e.
// Stage order: W0-x, W0-h, then Ws{0,1,2,3,4,6,5,7}.
__global__ void prep(const float* __restrict__ W0, const float* __restrict__ Ws,
                     char* __restrict__ wq) {
  int gid = blockIdx.x * 256 + threadIdx.x;
  const int mi[8] = {0, 1, 2, 3, 4, 6, 5, 7};
  int wv = gid / WSTRIDE;
  int r = gid - wv * WSTRIDE;
  int blk = r >> 10, b = r & 1023;
  int l = b >> 4, e = b & 15;
  int stage = blk >> 3, sb = blk & 7;
  int kt = sb >> 1, pt = sb & 1;
  int n = pt * 256 + wv * 16 + (l & 15);
  int k = kt * 64 + ((l >> 4) << 4) + e;
  float v;
  if (stage == 0) v = W0[k * 512 + n];
  else if (stage == 1) v = W0[(256 + k) * 512 + n];
  else v = Ws[(size_t)mi[stage - 2] * 131072 + k * 512 + n];
  wq[gid] = (char)(int)rintf(v * SW);
}

__global__ __launch_bounds__(1024) void darts9(const float* __restrict__ X,
                                               const float* __restrict__ Hin,
                                               const char* __restrict__ WQ,
                                               float* __restrict__ out) {
  __shared__ char A0XH[4096], A0XL[4096], A0HH[4096], A0HL[4096];
  __shared__ char SAH[4096], SAL[4096], SBH[4096], SBL[4096], SCH[4096], SCL[4096];

  const int tid = threadIdx.x, lane = tid & 63, wv = tid >> 6;  // 16 waves
  const int ncol = lane & 15, lrow = (lane >> 4) << 2;
  const int sc = wv * 16 + ncol;  // this lane's state column
  const int rb = blockIdx.x * 16;
  const char* wsrc = uniform_ptr(WQ + (size_t)wv * WSTRIDE);
  const int wvoff = lane * 16;
  const int xvoff = ((tid >> 6) << 10) + ((tid & 63) << 4);

  float hp[4];
#pragma unroll
  for (int j = 0; j < 4; ++j) hp[j] = Hin[(rb + lrow + j) * 256 + sc];
#pragma unroll
  for (int j = 0; j < 4; ++j) put_sv(A0HH, A0HL, lrow + j, sc, hp[j]);

  // prologue queue = [x1, bA8, d4] — identical shape to steady-state [x1, bA8, st4]
  float4 xr;
  i32x4 bA[8], bB[8];
  GLOAD(xr, xvoff, uniform_ptr(X + (size_t)rb * 256), 0);
  wissue(bA, wsrc, wvoff);
  {
    i32x4 d0, d1, d2, d3;
    GLOAD(d0, wvoff, wsrc, 0); GLOAD(d1, wvoff, wsrc, 1024);
    GLOAD(d2, wvoff, wsrc, 2048); GLOAD(d3, wvoff, wsrc, 3072);
  }

  float s0[4], s1[4], s2[4], s3[4], s5[4], ma[4];
  const float INVG = 1.0f / (4096.0f * SW);

  for (int t = 0; t < TT; ++t) {
    VMWAIT(12);  // retire x (oldest); bA8 + st4/d4 stay in flight
    {  // stage x_t regs -> int8 hi/lo LDS planes (x = hi/16 + lo/2048)
      int r = tid >> 6, c0 = (tid & 63) * 4;
      float xs[4] = {xr.x, xr.y, xr.z, xr.w};
      int hb[4], lb[4];
#pragma unroll
      for (int j = 0; j < 4; ++j) {
        float hf = rintf(fminf(fmaxf(xs[j] * 16.0f, -127.0f), 127.0f));
        lb[j] = (int)rintf((xs[j] - hf * (1.0f / 16.0f)) * 2048.0f);
        hb[j] = (int)hf;
      }
      int a = swz(r, c0);
      *(int*)(A0XH + a) = pack4(hb[0], hb[1], hb[2], hb[3]);
      *(int*)(A0XL + a) = pack4(lb[0], lb[1], lb[2], lb[3]);
    }
    barrier_ws();

    // --- P0: W0 x-part (bA); issue P1 -> bB ---
    i32x4 ch, cl, hh, hl;
    wissue(bB, wsrc + 8192, wvoff);
    VMWAIT(12);  // retire bA8 (st4 + bB8 = 12 remain)
    ch = (i32x4)(0); cl = (i32x4)(0); hh = (i32x4)(0); hl = (i32x4)(0);
#pragma unroll
    for (int kt = 0; kt < 4; ++kt) {
      i32x4 Axh = afrag(A0XH, lane, kt * 64);
      i32x4 Axl = afrag(A0XL, lane, kt * 64);
      ch = mi8(Axh, bA[kt * 2 + 0], ch);
      hh = mi8(Axh, bA[kt * 2 + 1], hh);
      cl = mi8(Axl, bA[kt * 2 + 0], cl);
      hl = mi8(Axl, bA[kt * 2 + 1], hl);
    }
    // x units are 2x state units: double before adding h terms
    ch = ch + ch; cl = cl + cl; hh = hh + hh; hl = hl + hl;

    // --- P1: W0 h-part (bB); issue P2 -> bA ---
    wissue(bA, wsrc + 2 * 8192, wvoff);
    VMWAIT(8);  // retire st4 + bB8
#pragma unroll
    for (int kt = 0; kt < 4; ++kt) {
      i32x4 Ahh = afrag(A0HH, lane, kt * 64);
      i32x4 Ahl = afrag(A0HL, lane, kt * 64);
      ch = mi8(Ahh, bB[kt * 2 + 0], ch);
      hh = mi8(Ahh, bB[kt * 2 + 1], hh);
      cl = mi8(Ahl, bB[kt * 2 + 0], cl);
      hl = mi8(Ahl, bB[kt * 2 + 1], hl);
    }
#pragma unroll
    for (int j = 0; j < 4; ++j) {
      float c = (float)(ch[j] * 128 + cl[j]) * INVG;
      float h = (float)(hh[j] * 128 + hl[j]) * INVG;
      s0[j] = __builtin_fmaf(fsig(c), ftanh(h) - hp[j], hp[j]);
      put_sv(SAH, SAL, lrow + j, sc, s0[j]);
    }
    barrier_ws();

#pragma unroll
    for (int j = 0; j < 4; ++j) ma[j] = 0.0f;

    // --- P2: s1 (sigmoid, Ws0) from SA(s0) -> SB; issue P3 -> bB ---
    wissue(bB, wsrc + 3 * 8192, wvoff);
    VMWAIT(8);
    gmm8(SAH, SAL, bA, lane, ch, cl, hh, hl);
    gepi<0, true, true>(ch, cl, hh, hl, s0, s1, ma, SBH, SBL, lrow, sc);
    barrier_ws();

    // --- P3: s2 relu -> SA; issue P4 -> bA ---
    wissue(bA, wsrc + 4 * 8192, wvoff);
    VMWAIT(8);
    gmm8(SBH, SBL, bB, lane, ch, cl, hh, hl);
    gepi<1, true, true>(ch, cl, hh, hl, s1, s2, ma, SAH, SAL, lrow, sc);
    // --- P4: s3 relu -> SC; issue P5 -> bB ---
    wissue(bB, wsrc + 5 * 8192, wvoff);
    VMWAIT(8);
    gmm8(SBH, SBL, bA, lane, ch, cl, hh, hl);
    gepi<1, true, true>(ch, cl, hh, hl, s1, s3, ma, SCH, SCL, lrow, sc);
    // --- P5: s4 identity (no store); issue P6 -> bA ---
    wissue(bA, wsrc + 6 * 8192, wvoff);
    VMWAIT(8);
    gmm8(SBH, SBL, bB, lane, ch, cl, hh, hl);
    gepi<3, false, false>(ch, cl, hh, hl, s1, s1, ma, nullptr, nullptr, lrow, sc);
    barrier_ws();

    // --- P6: s5 tanh (Ws4) from SA(s2) -> SB; issue P7 -> bB ---
    wissue(bB, wsrc + 7 * 8192, wvoff);
    VMWAIT(8);
    gmm8(SAH, SAL, bA, lane, ch, cl, hh, hl);
    gepi<2, true, true>(ch, cl, hh, hl, s2, s5, ma, SBH, SBL, lrow, sc);
    // --- P7: s7 tanh (Ws6) from SC(s3), no store; issue P8 -> bA ---
    wissue(bA, wsrc + 8 * 8192, wvoff);
    VMWAIT(8);
    gmm8(SCH, SCL, bB, lane, ch, cl, hh, hl);
    gepi<2, false, false>(ch, cl, hh, hl, s3, s3, ma, nullptr, nullptr, lrow, sc);
    barrier_ws();

    // --- P8: s6 sig (Ws5) from SB(s5); issue P9 -> bB, then x(t+1) ---
    wissue(bB, wsrc + 9 * 8192, wvoff);
    {
      int tn = (t + 1 < TT) ? t + 1 : TT - 1;
      GLOAD(xr, xvoff, uniform_ptr(X + ((size_t)tn * BB + rb) * 256), 0);
    }
    VMWAIT(9);  // retire bA8 (bB8 + x1 remain)
    gmm8(SBH, SBL, bA, lane, ch, cl, hh, hl);
    gepi<0, false, false>(ch, cl, hh, hl, s5, s5, ma, nullptr, nullptr, lrow, sc);
    // --- P9: s8 relu (Ws7) from SB(s5); issue P0' -> bA ---
    wissue(bA, wsrc, wvoff);
    VMWAIT(9);  // retire bB8 (x1 + bA8 remain)
    gmm8(SBH, SBL, bB, lane, ch, cl, hh, hl);
    gepi<1, false, false>(ch, cl, hh, hl, s5, s5, ma, nullptr, nullptr, lrow, sc);

    // h = mean(states 1..8); store hiddens[t] (4 stores ride the vm queue); restage h
#pragma unroll
    for (int j = 0; j < 4; ++j) hp[j] = ma[j] * 0.125f;
#pragma unroll
    for (int j = 0; j < 4; ++j)
      out[((size_t)t * BB + rb + lrow + j) * 256 + sc] = hp[j];
    if (t == TT - 1) {
#pragma unroll
      for (int j = 0; j < 4; ++j)
        out[((size_t)TT * BB + rb + lrow + j) * 256 + sc] = hp[j];
    }
#pragma unroll
    for (int j = 0; j < 4; ++j) put_sv(A0HH, A0HL, lrow + j, sc, hp[j]);
    // loop-top barrier orders A0X/A0H LDS writes for the next W0 stage
  }
  asm volatile("s_waitcnt vmcnt(0)" ::: "memory");  // drain tail loads/stores
}

extern "C" void kernel_launch(void* const* d_in, const int* in_sizes, int n_in,
                              void* d_out, int out_size, void* d_ws, size_t ws_size,
                              hipStream_t stream) {
  (void)in_sizes; (void)n_in; (void)out_size; (void)ws_size;
  const float* X = (const float*)d_in[0];
  const float* Hin = (const float*)d_in[1];
  const float* W0 = (const float*)d_in[2];
  const float* Ws = (const float*)d_in[3];
  char* wq = (char*)d_ws;  // 16 waves * 80 KiB = 1.28 MB
  float* out = (float*)d_out;

  prep<<<5120, 256, 0, stream>>>(W0, Ws, wq);
  darts9<<<16, 1024, 0, stream>>>(X, Hin, wq, out);
}